// Round 6
// baseline (212.825 us; speedup 1.0000x reference)
//
#include <hip/hip_runtime.h>
#include <hip/hip_bf16.h>
#include <math.h>

// ---------------------------------------------------------------------------
// CausalSelfAttention: B=2, S=2048, D=1024, H=16, Hd=64. f32 in / f32 out.
// R21: attn is LDS-pipe bound (R20 model: per-CU DS time ~= measured 71.6us;
// MfmaUtil 9%). Fix = amortize K/V LDS reads over 2x more MFMA: each wave
// now owns 4 q-sets (16 rows x 4 tiles {t,15-t,16+t,31-t}), block covers the
// 4 tiles, grid 256 = 1 block/CU. K/V staged once per kt feeds 4 tiles ->
// per-CU ds_read_b128 ops drop 2.3x. Work/block = 66 units uniform; kt-max
// 25..32 (~11% tail, unavoidable for sum-balanced groups). Two-barrier
// staging (proven R18 structure; R20's dbuf/1-barrier regressed). LDS 55KB,
// launch_bounds(256,1) for VGPR headroom (~190 est, 1 blk/CU anyway).
// gemm BK=64+swizzle kept from R20 (gained ~20us).
// ---------------------------------------------------------------------------

typedef short bfrag __attribute__((ext_vector_type(8)));   // 8 bf16 = 4 VGPR
typedef float f32x4 __attribute__((ext_vector_type(4)));

__device__ __forceinline__ float bf2f(ushort u) {
    union { uint i; float f; } v; v.i = ((uint)u) << 16; return v.f;
}
__device__ __forceinline__ ushort f2bf(float f) {
    union { uint i; float f; } v; v.f = f;
    uint u = v.i;
    return (ushort)((u + 0x7fffu + ((u >> 16) & 1u)) >> 16);  // RNE
}
__device__ __forceinline__ ushort f2bf_hw(float f) {
    union { __hip_bfloat16 b; ushort u; } cv;
    cv.b = __float2bfloat16(f);                 // native cvt on gfx950 (RNE)
    return cv.u;
}

#define MFMA16 __builtin_amdgcn_mfma_f32_16x16x32_bf16

__device__ __forceinline__ void gl_lds16(const ushort* g, ushort* l) {
    __builtin_amdgcn_global_load_lds(
        (const __attribute__((address_space(1))) void*)g,
        (__attribute__((address_space(3))) void*)l, 16, 0, 0);
}

// ---------------------------------------------------------------------------
// Kernel 0a: f32 -> bf16 convert (xb = x; wb = [Wq;Wkv]).  (unchanged)
// ---------------------------------------------------------------------------
__global__ __launch_bounds__(256)
void cvt_bf16(const float* __restrict__ x, const float* __restrict__ wq,
              const float* __restrict__ wkv, ushort* __restrict__ xb,
              ushort* __restrict__ wb)
{
    const size_t NX = 4096u * 1024u, NWQ = 1024u * 1024u;
    size_t i8 = ((size_t)blockIdx.x * 256 + threadIdx.x) * 8;
    const float* src;
    ushort* dst;
    if (i8 < NX) { src = x + i8; dst = xb + i8; }
    else {
        size_t j = i8 - NX;
        dst = wb + j;
        src = (j < NWQ) ? (wq + j) : (wkv + (j - NWQ));
    }
    float4 a = *(const float4*)(src);
    float4 c = *(const float4*)(src + 4);
    ushort u[8];
    u[0] = f2bf(a.x); u[1] = f2bf(a.y); u[2] = f2bf(a.z); u[3] = f2bf(a.w);
    u[4] = f2bf(c.x); u[5] = f2bf(c.y); u[6] = f2bf(c.z); u[7] = f2bf(c.w);
    *(uint4*)dst = *(uint4*)u;
}

// ---------------------------------------------------------------------------
// Kernel 0b: rope table tab[s][fi] = (cos,sin)(s * 10000^(-fi/32)). (unchanged)
// ---------------------------------------------------------------------------
__global__ __launch_bounds__(256)
void rope_table(float2* __restrict__ tab)
{
    int t  = blockIdx.x * 256 + threadIdx.x;   // 65536
    int fi = t & 31, s = t >> 5;
    float invf = (float)exp((double)fi * -0.28782313662425574);
    float thf  = (float)s * invf;
    const double TWO_PI = 6.283185307179586476925287;
    double th = (double)thf;
    double kq = __builtin_rint(th * (1.0 / TWO_PI));
    float r = (float)(th - kq * TWO_PI);
    tab[t] = make_float2(cosf(r), sinf(r));
}

// ---------------------------------------------------------------------------
// Kernel 1 (R20): QKV GEMM, BK=64, swizzled LDS (conflict-free frag reads),
// fused RoPE/V-transpose epilogue.  (unchanged from R20)
// ---------------------------------------------------------------------------
__global__ __launch_bounds__(256)
void gemm_qkv(const ushort* __restrict__ xb, const ushort* __restrict__ wb,
              const float2* __restrict__ tab, ushort* __restrict__ Qb,
              ushort* __restrict__ Kb, ushort* __restrict__ Vt)
{
    __shared__ ushort Ash[128][64];
    __shared__ ushort Bsh[128][64];

    const int tid  = threadIdx.x;
    const int lane = tid & 63, wv = tid >> 6;
    const int quad = lane >> 4, li = lane & 15;
    const int m0 = blockIdx.x * 128, n0 = blockIdx.y * 128;

    f32x4 acc[2][8];
#pragma unroll
    for (int mi = 0; mi < 2; mi++)
#pragma unroll
        for (int j = 0; j < 8; j++) acc[mi][j] = (f32x4){0.f, 0.f, 0.f, 0.f};

    const int r8  = lane >> 3;
    const int gch = ((lane & 7) ^ r8) * 8;
    const ushort* gA = xb + (size_t)(m0 + wv * 32 + r8) * 1024 + gch;
    const ushort* gB = wb + (size_t)(n0 + wv * 32 + r8) * 1024 + gch;

    for (int k0 = 0; k0 < 1024; k0 += 64) {
        __syncthreads();
#pragma unroll
        for (int c = 0; c < 4; c++) {
            gl_lds16(gA + (size_t)(c * 8) * 1024 + k0, &Ash[wv * 32 + c * 8][0]);
            gl_lds16(gB + (size_t)(c * 8) * 1024 + k0, &Bsh[wv * 32 + c * 8][0]);
        }
        __syncthreads();

        const int sw = li & 7;
#pragma unroll
        for (int ks = 0; ks < 2; ks++) {
            bfrag af[2], bf[8];
#pragma unroll
            for (int mi = 0; mi < 2; mi++)
                af[mi] = *(const bfrag*)
                    &Ash[wv * 32 + mi * 16 + li][(((ks << 2) | quad) ^ sw) * 8];
#pragma unroll
            for (int j = 0; j < 8; j++)
                bf[j] = *(const bfrag*)
                    &Bsh[j * 16 + li][(((ks << 2) | quad) ^ sw) * 8];
#pragma unroll
            for (int mi = 0; mi < 2; mi++)
#pragma unroll
                for (int j = 0; j < 8; j++)
                    acc[mi][j] = MFMA16(af[mi], bf[j], acc[mi][j], 0, 0, 0);
        }
    }

    if (n0 < 1024) {
        const int hbase = n0 >> 6;
#pragma unroll
        for (int mi = 0; mi < 2; mi++)
#pragma unroll
            for (int r = 0; r < 4; r++) {
                int m = m0 + wv * 32 + mi * 16 + quad * 4 + r;
                int bb = m >> 11, s = m & 2047;
                float2 t0 = tab[s * 32 + li];
                float2 t1 = tab[s * 32 + li + 16];
#pragma unroll
                for (int j = 0; j < 8; j++) {
                    float v  = acc[mi][j][r];
                    float vp = acc[mi][j ^ 2][r];
                    float2 tt = (j & 1) ? t1 : t0;
                    float rh = (j & 2) ? vp : -vp;
                    int h = hbase + (j >> 2), hd = (j & 3) * 16 + li;
                    Qb[(size_t)((bb * 16 + h) * 2048 + s) * 64 + hd] =
                        f2bf(v * tt.x + rh * tt.y);
                }
            }
    } else {
        const int h = (n0 - 1024) >> 7;
        const int li2 = li >> 1;
        if ((li & 1) == 0) {
#pragma unroll
            for (int mi = 0; mi < 2; mi++)
#pragma unroll
                for (int r = 0; r < 4; r++) {
                    int m = m0 + wv * 32 + mi * 16 + quad * 4 + r;
                    int bb = m >> 11, s = m & 2047;
                    float2 tt4[4];
#pragma unroll
                    for (int jj = 0; jj < 4; jj++)
                        tt4[jj] = tab[s * 32 + jj * 8 + li2];
#pragma unroll
                    for (int j = 0; j < 8; j++) {
                        float v  = acc[mi][j][r];
                        float vp = acc[mi][j ^ 4][r];
                        float2 tt = tt4[j & 3];
                        float rh = (j & 4) ? vp : -vp;
                        int hd = j * 8 + li2;
                        Kb[(size_t)((bb * 16 + h) * 2048 + s) * 64 + hd] =
                            f2bf(v * tt.x + rh * tt.y);
                    }
                }
        } else {
#pragma unroll
            for (int mi = 0; mi < 2; mi++) {
                int m4 = m0 + wv * 32 + mi * 16 + quad * 4;
                int bb = m4 >> 11, s0 = m4 & 2047;
#pragma unroll
                for (int j = 0; j < 8; j++) {
                    int hd = j * 8 + li2;
                    ushort u4[4];
#pragma unroll
                    for (int r = 0; r < 4; r++) u4[r] = f2bf(acc[mi][j][r]);
                    *(ushort4*)&Vt[(size_t)((bb * 16 + h) * 64 + hd) * 2048 + s0] =
                        *(ushort4*)u4;
                }
            }
        }
    }
}

// ---------------------------------------------------------------------------
// Kernel 2 (R21): 4-tile causal flash attention, LDS-read amortized.
// Block = (b,h) x tiles {t,15-t,16+t,31-t}; 4 waves; wave w owns rows
// w*16..+15 of all 4 tiles (q = li, swapped-QK^T). K/V staged once per kt
// (two-barrier, reg prefetch) feeds up to 16 QK + 16 PV MFMA per wave.
// ---------------------------------------------------------------------------
__global__ __launch_bounds__(256, 1)
void attn(const ushort* __restrict__ Qb, const ushort* __restrict__ Kb,
          const ushort* __restrict__ Vt, float* __restrict__ out)
{
    __shared__ ushort Ksh[64][72];
    __shared__ ushort Vsh[64][72];
    __shared__ ushort Psh[4][4][16][72];   // [wave][set]

    const int tid  = threadIdx.x;
    const int lane = tid & 63, w = tid >> 6;
    const int quad = lane >> 4, li = lane & 15;

    const int l  = (int)blockIdx.x;        // 256 blocks, 1 per CU
    const int bh = l & 31;                 // head per XCD: l%8 == bh%8
    const int t  = l >> 5;                 // 0..7
    const int b = bh >> 4, h = bh & 15;

    const int qts[4] = {t, 15 - t, 16 + t, 31 - t};
    const int ktmax = 31 - t;

    int rows[4];
    bfrag qa[4][2];
#pragma unroll
    for (int s = 0; s < 4; s++) {
        rows[s] = qts[s] * 64 + w * 16 + li;
        const ushort* qp = Qb + (size_t)(bh * 2048 + rows[s]) * 64;
        qa[s][0] = *(const bfrag*)(qp + quad * 8);
        qa[s][1] = *(const bfrag*)(qp + quad * 8 + 32);
    }

    f32x4 o[4][4];
#pragma unroll
    for (int s = 0; s < 4; s++)
#pragma unroll
        for (int j = 0; j < 4; j++) o[s][j] = (f32x4){0.f, 0.f, 0.f, 0.f};
    float lrow[4] = {0.f, 0.f, 0.f, 0.f};

    const int srow = tid >> 2, sc0 = (tid & 3) * 16;
    const ushort* kbase = Kb + (size_t)bh * 2048 * 64;
    const ushort* vbase = Vt + (size_t)bh * 64 * 2048;

    // preload kt=0 (16 VGPRs of prefetch state)
    uint4 ka, kb_, va, vb_;
    {
        const ushort* gk = kbase + (size_t)srow * 64 + sc0;
        ka  = *(const uint4*)gk;
        kb_ = *(const uint4*)(gk + 8);
        const ushort* gv = vbase + (size_t)srow * 2048 + sc0;
        va  = *(const uint4*)gv;
        vb_ = *(const uint4*)(gv + 8);
    }

    const float C = 0.125f * 1.4426950408889634f;   // scale * log2(e)

    for (int kt = 0; kt <= ktmax; ++kt) {
        __syncthreads();
        *(uint4*)&Ksh[srow][sc0]     = ka;
        *(uint4*)&Ksh[srow][sc0 + 8] = kb_;
        *(uint4*)&Vsh[srow][sc0]     = va;
        *(uint4*)&Vsh[srow][sc0 + 8] = vb_;
        __syncthreads();

        if (kt < ktmax) {     // prefetch next tile; latency hidden by compute
            const ushort* gk = kbase + (size_t)((kt + 1) * 64 + srow) * 64 + sc0;
            ka  = *(const uint4*)gk;
            kb_ = *(const uint4*)(gk + 8);
            const ushort* gv = vbase + (size_t)srow * 2048 + (kt + 1) * 64 + sc0;
            va  = *(const uint4*)gv;
            vb_ = *(const uint4*)(gv + 8);
        }

        float rs[4] = {0.f, 0.f, 0.f, 0.f};

        // --- per-j: one K-frag read feeds up to 4 tiles (8 QK MFMA) ---
#pragma unroll
        for (int j = 0; j < 4; j++) {
            bfrag kf0 = *(const bfrag*)&Ksh[j * 16 + li][quad * 8];
            bfrag kf1 = *(const bfrag*)&Ksh[j * 16 + li][quad * 8 + 32];

            f32x4 z[4];
            __builtin_amdgcn_s_setprio(1);
#pragma unroll
            for (int s = 0; s < 4; s++) {
                if (kt <= qts[s]) {
                    f32x4 zz = (f32x4){0.f, 0.f, 0.f, 0.f};
                    zz = MFMA16(kf0, qa[s][0], zz, 0, 0, 0);
                    zz = MFMA16(kf1, qa[s][1], zz, 0, 0, 0);
                    z[s] = zz;
                }
            }
            __builtin_amdgcn_s_setprio(0);

            const int kg0 = kt * 64 + j * 16 + quad * 4;
#pragma unroll
            for (int s = 0; s < 4; s++) {
                if (kt <= qts[s]) {
                    if (kt == qts[s]) {   // diagonal tile: causal mask
#pragma unroll
                        for (int r = 0; r < 4; r++)
                            z[s][r] = (kg0 + r <= rows[s]) ? z[s][r] : -3.0e38f;
                    }
                    ushort pk[4];
#pragma unroll
                    for (int r = 0; r < 4; r++) {
                        float pv = exp2f(z[s][r] * C);
                        rs[s] += pv;
                        pk[r] = f2bf_hw(pv);
                    }
                    *(ushort4*)&Psh[w][s][li][j * 16 + quad * 4] = *(ushort4*)pk;
                }
            }
        }

        // complete row-sums for q=li across the 4 quads
#pragma unroll
        for (int s = 0; s < 4; s++) {
            if (kt <= qts[s]) {
                float v = rs[s];
                v += __shfl_xor(v, 16);
                v += __shfl_xor(v, 32);
                lrow[s] += v;
            }
        }

        // --- P: LDS -> A-fragments (wave-private Psh) ---
        asm volatile("s_waitcnt lgkmcnt(0)" ::: "memory");
        bfrag pa[4][2];
#pragma unroll
        for (int s = 0; s < 4; s++) {
            if (kt <= qts[s]) {
                pa[s][0] = *(const bfrag*)&Psh[w][s][li][quad * 8];
                pa[s][1] = *(const bfrag*)&Psh[w][s][li][quad * 8 + 32];
            }
        }

        // --- PV: one V-frag read feeds up to 4 tiles (8 PV MFMA) ---
#pragma unroll
        for (int j = 0; j < 4; j++) {
            bfrag vf0 = *(const bfrag*)&Vsh[j * 16 + li][quad * 8];
            bfrag vf1 = *(const bfrag*)&Vsh[j * 16 + li][quad * 8 + 32];
            __builtin_amdgcn_s_setprio(1);
#pragma unroll
            for (int s = 0; s < 4; s++) {
                if (kt <= qts[s]) {
                    o[s][j] = MFMA16(pa[s][0], vf0, o[s][j], 0, 0, 0);
                    o[s][j] = MFMA16(pa[s][1], vf1, o[s][j], 0, 0, 0);
                }
            }
            __builtin_amdgcn_s_setprio(0);
        }
    }

    // epilogue: redistribute l (held at lane li == q) to q = quad*4+r
#pragma unroll
    for (int s = 0; s < 4; s++) {
        float lf[4];
#pragma unroll
        for (int r = 0; r < 4; r++)
            lf[r] = __shfl(lrow[s], (lane & 48) + quad * 4 + r);
#pragma unroll
        for (int j = 0; j < 4; j++)
#pragma unroll
            for (int r = 0; r < 4; r++) {
                int sr = qts[s] * 64 + w * 16 + quad * 4 + r;
                out[(size_t)(b * 2048 + sr) * 1024 + h * 64 + j * 16 + li] =
                    o[s][j][r] / lf[r];
            }
    }
}

// ---------------------------------------------------------------------------
extern "C" void kernel_launch(void* const* d_in, const int* in_sizes, int n_in,
                              void* d_out, int out_size, void* d_ws, size_t ws_size,
                              hipStream_t stream)
{
    (void)in_sizes; (void)n_in; (void)out_size; (void)ws_size;
    const float* x   = (const float*)d_in[0];   // (2,2048,1024) f32
    const float* wq  = (const float*)d_in[1];   // (1024,1024)  f32
    const float* wkv = (const float*)d_in[2];   // (2048,1024)  f32
    // d_in[3] = causal mask — computed analytically

    ushort* xb = (ushort*)d_ws;                       // 4096x1024 bf16
    ushort* wb = xb + (size_t)4096 * 1024;            // 3072x1024 bf16
    float2* tab = (float2*)(wb + (size_t)3072 * 1024); // 2048x32 (cos,sin)
    ushort* Qb = (ushort*)(tab + 65536);              // (B,H,S,Hd)
    ushort* Kb = Qb + (size_t)2 * 16 * 2048 * 64;     // (B,H,S,Hd)
    ushort* Vt = Kb + (size_t)2 * 16 * 2048 * 64;     // (B,H,Hd,S)
    float* out = (float*)d_out;                       // f32 output

    cvt_bf16<<<3584, 256, 0, stream>>>(x, wq, wkv, xb, wb);
    rope_table<<<256, 256, 0, stream>>>(tab);
    dim3 g1(32, 24);
    gemm_qkv<<<g1, 256, 0, stream>>>(xb, wb, tab, Qb, Kb, Vt);
    attn<<<256, 256, 0, stream>>>(Qb, Kb, Vt, out);
}

// Round 7
// 199.253 us; speedup vs baseline: 1.0681x; 1.0681x over previous
//
#include <hip/hip_runtime.h>
#include <hip/hip_bf16.h>
#include <math.h>

// ---------------------------------------------------------------------------
// CausalSelfAttention: B=2, S=2048, D=1024, H=16, Hd=64. f32 in / f32 out.
// R22: attn rebuilt on mfma_32x32x16. Wave owns 32 q-rows (q = lane&31 in
// C-layout), 2-wave/128-thr blocks, 1024 blocks = 4/CU = 8 waves/CU (the
// proven-occupancy regime, unlike R21's 1 wave/SIMD collapse).
// - P stays IN REGISTERS: QK^T reg-order == PV A-operand contraction order
//   when V's s-dim is stored bit2<->bit3-swapped per 16-group (sigma, done
//   free in gemm's V-epilogue). No Psh, no P LDS round-trip.
// - K/V: [64][64] LDS, XOR chunk-swizzle (linear gl_lds dest, pre-swizzled
//   global source, XOR'd reads - rule both-sides), double-buffered, ONE
//   barrier/iter; async gl_lds drains at the barrier (m97 pattern).
// - grid (32,32): bh=x pins head to XCD (FETCH 12.4MB), qt=(x+y)&31 balance.
// gemm/cvt/rope from R20, gemm V-write sigma-swapped.
// ---------------------------------------------------------------------------

typedef short bfrag __attribute__((ext_vector_type(8)));   // 8 bf16 = 4 VGPR
typedef float f32x4 __attribute__((ext_vector_type(4)));
typedef float f32x16 __attribute__((ext_vector_type(16)));

__device__ __forceinline__ float bf2f(ushort u) {
    union { uint i; float f; } v; v.i = ((uint)u) << 16; return v.f;
}
__device__ __forceinline__ ushort f2bf(float f) {
    union { uint i; float f; } v; v.f = f;
    uint u = v.i;
    return (ushort)((u + 0x7fffu + ((u >> 16) & 1u)) >> 16);  // RNE
}
__device__ __forceinline__ ushort f2bf_hw(float f) {
    union { __hip_bfloat16 b; ushort u; } cv;
    cv.b = __float2bfloat16(f);                 // native cvt on gfx950 (RNE)
    return cv.u;
}

#define MFMA16 __builtin_amdgcn_mfma_f32_16x16x32_bf16
#define MFMA32 __builtin_amdgcn_mfma_f32_32x32x16_bf16

__device__ __forceinline__ void gl_lds16(const ushort* g, ushort* l) {
    __builtin_amdgcn_global_load_lds(
        (const __attribute__((address_space(1))) void*)g,
        (__attribute__((address_space(3))) void*)l, 16, 0, 0);
}

// ---------------------------------------------------------------------------
// Kernel 0a: f32 -> bf16 convert (xb = x; wb = [Wq;Wkv]).  (unchanged)
// ---------------------------------------------------------------------------
__global__ __launch_bounds__(256)
void cvt_bf16(const float* __restrict__ x, const float* __restrict__ wq,
              const float* __restrict__ wkv, ushort* __restrict__ xb,
              ushort* __restrict__ wb)
{
    const size_t NX = 4096u * 1024u, NWQ = 1024u * 1024u;
    size_t i8 = ((size_t)blockIdx.x * 256 + threadIdx.x) * 8;
    const float* src;
    ushort* dst;
    if (i8 < NX) { src = x + i8; dst = xb + i8; }
    else {
        size_t j = i8 - NX;
        dst = wb + j;
        src = (j < NWQ) ? (wq + j) : (wkv + (j - NWQ));
    }
    float4 a = *(const float4*)(src);
    float4 c = *(const float4*)(src + 4);
    ushort u[8];
    u[0] = f2bf(a.x); u[1] = f2bf(a.y); u[2] = f2bf(a.z); u[3] = f2bf(a.w);
    u[4] = f2bf(c.x); u[5] = f2bf(c.y); u[6] = f2bf(c.z); u[7] = f2bf(c.w);
    *(uint4*)dst = *(uint4*)u;
}

// ---------------------------------------------------------------------------
// Kernel 0b: rope table tab[s][fi] = (cos,sin)(s * 10000^(-fi/32)). (unchanged)
// ---------------------------------------------------------------------------
__global__ __launch_bounds__(256)
void rope_table(float2* __restrict__ tab)
{
    int t  = blockIdx.x * 256 + threadIdx.x;   // 65536
    int fi = t & 31, s = t >> 5;
    float invf = (float)exp((double)fi * -0.28782313662425574);
    float thf  = (float)s * invf;
    const double TWO_PI = 6.283185307179586476925287;
    double th = (double)thf;
    double kq = __builtin_rint(th * (1.0 / TWO_PI));
    float r = (float)(th - kq * TWO_PI);
    tab[t] = make_float2(cosf(r), sinf(r));
}

// ---------------------------------------------------------------------------
// Kernel 1 (R20 + sigma V): QKV GEMM, BK=64, swizzled LDS, fused RoPE.
// V-epilogue stores s-index with bits 2<->3 swapped within each 16-group so
// attn's PV B-operand slot order equals the in-register P reg order.
// ---------------------------------------------------------------------------
__global__ __launch_bounds__(256)
void gemm_qkv(const ushort* __restrict__ xb, const ushort* __restrict__ wb,
              const float2* __restrict__ tab, ushort* __restrict__ Qb,
              ushort* __restrict__ Kb, ushort* __restrict__ Vt)
{
    __shared__ ushort Ash[128][64];
    __shared__ ushort Bsh[128][64];

    const int tid  = threadIdx.x;
    const int lane = tid & 63, wv = tid >> 6;
    const int quad = lane >> 4, li = lane & 15;
    const int m0 = blockIdx.x * 128, n0 = blockIdx.y * 128;

    f32x4 acc[2][8];
#pragma unroll
    for (int mi = 0; mi < 2; mi++)
#pragma unroll
        for (int j = 0; j < 8; j++) acc[mi][j] = (f32x4){0.f, 0.f, 0.f, 0.f};

    const int r8  = lane >> 3;
    const int gch = ((lane & 7) ^ r8) * 8;
    const ushort* gA = xb + (size_t)(m0 + wv * 32 + r8) * 1024 + gch;
    const ushort* gB = wb + (size_t)(n0 + wv * 32 + r8) * 1024 + gch;

    for (int k0 = 0; k0 < 1024; k0 += 64) {
        __syncthreads();
#pragma unroll
        for (int c = 0; c < 4; c++) {
            gl_lds16(gA + (size_t)(c * 8) * 1024 + k0, &Ash[wv * 32 + c * 8][0]);
            gl_lds16(gB + (size_t)(c * 8) * 1024 + k0, &Bsh[wv * 32 + c * 8][0]);
        }
        __syncthreads();

        const int sw = li & 7;
#pragma unroll
        for (int ks = 0; ks < 2; ks++) {
            bfrag af[2], bf[8];
#pragma unroll
            for (int mi = 0; mi < 2; mi++)
                af[mi] = *(const bfrag*)
                    &Ash[wv * 32 + mi * 16 + li][(((ks << 2) | quad) ^ sw) * 8];
#pragma unroll
            for (int j = 0; j < 8; j++)
                bf[j] = *(const bfrag*)
                    &Bsh[j * 16 + li][(((ks << 2) | quad) ^ sw) * 8];
#pragma unroll
            for (int mi = 0; mi < 2; mi++)
#pragma unroll
                for (int j = 0; j < 8; j++)
                    acc[mi][j] = MFMA16(af[mi], bf[j], acc[mi][j], 0, 0, 0);
        }
    }

    if (n0 < 1024) {
        const int hbase = n0 >> 6;
#pragma unroll
        for (int mi = 0; mi < 2; mi++)
#pragma unroll
            for (int r = 0; r < 4; r++) {
                int m = m0 + wv * 32 + mi * 16 + quad * 4 + r;
                int bb = m >> 11, s = m & 2047;
                float2 t0 = tab[s * 32 + li];
                float2 t1 = tab[s * 32 + li + 16];
#pragma unroll
                for (int j = 0; j < 8; j++) {
                    float v  = acc[mi][j][r];
                    float vp = acc[mi][j ^ 2][r];
                    float2 tt = (j & 1) ? t1 : t0;
                    float rh = (j & 2) ? vp : -vp;
                    int h = hbase + (j >> 2), hd = (j & 3) * 16 + li;
                    Qb[(size_t)((bb * 16 + h) * 2048 + s) * 64 + hd] =
                        f2bf(v * tt.x + rh * tt.y);
                }
            }
    } else {
        const int h = (n0 - 1024) >> 7;
        const int li2 = li >> 1;
        if ((li & 1) == 0) {
#pragma unroll
            for (int mi = 0; mi < 2; mi++)
#pragma unroll
                for (int r = 0; r < 4; r++) {
                    int m = m0 + wv * 32 + mi * 16 + quad * 4 + r;
                    int bb = m >> 11, s = m & 2047;
                    float2 tt4[4];
#pragma unroll
                    for (int jj = 0; jj < 4; jj++)
                        tt4[jj] = tab[s * 32 + jj * 8 + li2];
#pragma unroll
                    for (int j = 0; j < 8; j++) {
                        float v  = acc[mi][j][r];
                        float vp = acc[mi][j ^ 4][r];
                        float2 tt = tt4[j & 3];
                        float rh = (j & 4) ? vp : -vp;
                        int hd = j * 8 + li2;
                        Kb[(size_t)((bb * 16 + h) * 2048 + s) * 64 + hd] =
                            f2bf(v * tt.x + rh * tt.y);
                    }
                }
        } else {
#pragma unroll
            for (int mi = 0; mi < 2; mi++) {
                int m4 = m0 + wv * 32 + mi * 16 + quad * 4;
                int bb = m4 >> 11, s0 = m4 & 2047;
                // sigma: swap bits 2<->3 of s within its 16-group (self-inverse;
                // s0..s0+3 stay contiguous since bits 0,1 untouched)
                int sl0 = (s0 & ~12) | (((s0 >> 2) & 1) << 3) | (((s0 >> 3) & 1) << 2);
#pragma unroll
                for (int j = 0; j < 8; j++) {
                    int hd = j * 8 + li2;
                    ushort u4[4];
#pragma unroll
                    for (int r = 0; r < 4; r++) u4[r] = f2bf(acc[mi][j][r]);
                    *(ushort4*)&Vt[(size_t)((bb * 16 + h) * 64 + hd) * 2048 + sl0] =
                        *(ushort4*)u4;
                }
            }
        }
    }
}

// ---------------------------------------------------------------------------
// Kernel 2 (R22): causal flash attention, mfma_32x32x16, in-register P.
// 128 thr = 2 waves; wave w: q-rows qt*64 + w*32 .. +32 (q = lane&31).
// QK: A = K-tile (k=lane&31 rows from swizzled LDS), B = Q (regs).
// P = exp2(S*C) in regs; reg-order == PV A contraction order (sigma-V).
// PV: A = P (regs), B = V (swizzled LDS). No Psh. Dbuf + 1 barrier/iter.
// ---------------------------------------------------------------------------
__global__ __launch_bounds__(128, 2)
void attn(const ushort* __restrict__ Qb, const ushort* __restrict__ Kb,
          const ushort* __restrict__ Vt, float* __restrict__ out)
{
    __shared__ ushort Ksh[2][64][64];
    __shared__ ushort Vsh[2][64][64];

    const int tid  = threadIdx.x;           // 0..127
    const int lane = tid & 63, w = tid >> 6;
    const int q5 = lane & 31, hi = lane >> 5;

    const int bh = (int)blockIdx.x;                       // head -> XCD bh%8
    const int qt = ((int)blockIdx.x + (int)blockIdx.y) & 31;  // balanced
    const int b = bh >> 4, h = bh & 15;

    const int qrow = qt * 64 + w * 32 + q5;   // this lane's q (C-layout col)

    // Q B-frags: 4 hd-steps of 16, in regs for the whole kernel
    bfrag qf[4];
    {
        const ushort* qp = Qb + (size_t)(bh * 2048 + qrow) * 64 + hi * 8;
#pragma unroll
        for (int st = 0; st < 4; st++) qf[st] = *(const bfrag*)(qp + st * 16);
    }

    f32x16 o0, o1;                            // hd 0..31 / 32..63
#pragma unroll
    for (int r = 0; r < 16; r++) { o0[r] = 0.f; o1[r] = 0.f; }
    float lrow = 0.f;

    const ushort* kbase = Kb + (size_t)bh * 2048 * 64;
    const ushort* vbase = Vt + (size_t)bh * 64 * 2048;

    const int sr8 = lane >> 3, sc8 = lane & 7;

    // prologue: stage kt=0 into buf0 (async; drained at first barrier)
#pragma unroll
    for (int c = 0; c < 4; c++) {
        int row0 = c * 16 + 8 * w;            // wave-uniform LDS base row
        int row  = row0 + sr8;
        int ch   = (sc8 ^ (row & 7)) * 8;     // pre-swizzled global chunk
        gl_lds16(kbase + (size_t)row * 64 + ch, &Ksh[0][row0][0]);
        gl_lds16(vbase + (size_t)row * 2048 + ch, &Vsh[0][row0][0]);
    }

    const float C = 0.125f * 1.4426950408889634f;   // scale * log2(e)

    for (int kt = 0; kt <= qt; ++kt) {
        const int cur = kt & 1;
        __syncthreads();   // auto vmcnt(0): buf[cur] loads landed; prev reads done

        if (kt < qt) {     // async-stage kt+1 into buf cur^1, overlaps compute
#pragma unroll
            for (int c = 0; c < 4; c++) {
                int row0 = c * 16 + 8 * w;
                int row  = row0 + sr8;
                int ch   = (sc8 ^ (row & 7)) * 8;
                gl_lds16(kbase + (size_t)((kt + 1) * 64 + row) * 64 + ch,
                         &Ksh[cur ^ 1][row0][0]);
                gl_lds16(vbase + (size_t)row * 2048 + (kt + 1) * 64 + ch,
                         &Vsh[cur ^ 1][row0][0]);
            }
        }

        float rs = 0.f;
#pragma unroll
        for (int sub = 0; sub < 2; sub++) {
            const int krow = sub * 32 + q5;   // A-operand k-row for this lane

            // --- QK^T: S[k][q], 4 hd-steps chained ---
            f32x16 z;
#pragma unroll
            for (int r = 0; r < 16; r++) z[r] = 0.f;
            __builtin_amdgcn_s_setprio(1);
#pragma unroll
            for (int st = 0; st < 4; st++) {
                bfrag kf = *(const bfrag*)
                    &Ksh[cur][krow][(((st << 1) | hi) ^ (krow & 7)) * 8];
                z = MFMA32(kf, qf[st], z, 0, 0, 0);
            }
            __builtin_amdgcn_s_setprio(0);

            // --- causal mask: diagonal tile only; k from C-layout row formula ---
            if (kt == qt) {
#pragma unroll
                for (int r = 0; r < 16; r++) {
                    int kg = kt * 64 + sub * 32 + (r & 3) + 8 * (r >> 2) + 4 * hi;
                    z[r] = (kg <= qrow) ? z[r] : -3.0e38f;
                }
            }

            // --- P = exp2(S*C), in regs; row-sum partial ---
            float p[16];
#pragma unroll
            for (int r = 0; r < 16; r++) { p[r] = exp2f(z[r] * C); rs += p[r]; }

            // --- pack to PV A-frags: reg-order IS contraction order (sigma-V) ---
            uint pw[8];
#pragma unroll
            for (int i = 0; i < 8; i++)
                pw[i] = (uint)f2bf_hw(p[2 * i]) |
                        ((uint)f2bf_hw(p[2 * i + 1]) << 16);
            union { uint u[4]; bfrag f; } pa0, pa1;
#pragma unroll
            for (int i = 0; i < 4; i++) { pa0.u[i] = pw[i]; pa1.u[i] = pw[4 + i]; }

            // --- PV: o[ht] += P_chunk * V_chunk (V slot-stored) ---
            __builtin_amdgcn_s_setprio(1);
#pragma unroll
            for (int st2 = 0; st2 < 2; st2++) {
                bfrag pf = st2 ? pa1.f : pa0.f;
                const int colu = sub * 4 + st2 * 2 + hi;   // s-slot chunk
#pragma unroll
                for (int ht = 0; ht < 2; ht++) {
                    int vrow = ht * 32 + q5;               // hd row
                    bfrag vf = *(const bfrag*)
                        &Vsh[cur][vrow][(colu ^ (vrow & 7)) * 8];
                    if (ht == 0) o0 = MFMA32(pf, vf, o0, 0, 0, 0);
                    else         o1 = MFMA32(pf, vf, o1, 0, 0, 0);
                }
            }
            __builtin_amdgcn_s_setprio(0);
        }

        rs += __shfl_xor(rs, 32);   // column q total across lane halves
        lrow += rs;
    }

    // epilogue: out[b][q][h*64+hd] = O/l ; l held at lanes with lane&31 == q
#pragma unroll
    for (int r = 0; r < 16; r++) {
        int cr = (r & 3) + 8 * (r >> 2) + 4 * hi;
        float lv = __shfl(lrow, cr);
        int q = qt * 64 + w * 32 + cr;
        float* op = out + (size_t)(b * 2048 + q) * 1024 + h * 64 + q5;
        op[0]  = o0[r] / lv;
        op[32] = o1[r] / lv;
    }
}

// ---------------------------------------------------------------------------
extern "C" void kernel_launch(void* const* d_in, const int* in_sizes, int n_in,
                              void* d_out, int out_size, void* d_ws, size_t ws_size,
                              hipStream_t stream)
{
    (void)in_sizes; (void)n_in; (void)out_size; (void)ws_size;
    const float* x   = (const float*)d_in[0];   // (2,2048,1024) f32
    const float* wq  = (const float*)d_in[1];   // (1024,1024)  f32
    const float* wkv = (const float*)d_in[2];   // (2048,1024)  f32
    // d_in[3] = causal mask — computed analytically

    ushort* xb = (ushort*)d_ws;                       // 4096x1024 bf16
    ushort* wb = xb + (size_t)4096 * 1024;            // 3072x1024 bf16
    float2* tab = (float2*)(wb + (size_t)3072 * 1024); // 2048x32 (cos,sin)
    ushort* Qb = (ushort*)(tab + 65536);              // (B,H,S,Hd)
    ushort* Kb = Qb + (size_t)2 * 16 * 2048 * 64;     // (B,H,S,Hd)
    ushort* Vt = Kb + (size_t)2 * 16 * 2048 * 64;     // (B,H,Hd,S) sigma-slots
    float* out = (float*)d_out;                       // f32 output

    cvt_bf16<<<3584, 256, 0, stream>>>(x, wq, wkv, xb, wb);
    rope_table<<<256, 256, 0, stream>>>(tab);
    dim3 g1(32, 24);
    gemm_qkv<<<g1, 256, 0, stream>>>(xb, wb, tab, Qb, Kb, Vt);
    dim3 g4(32, 32);
    attn<<<g4, 128, 0, stream>>>(Qb, Kb, Vt, out);
}

// Round 9
// 182.281 us; speedup vs baseline: 1.1676x; 1.0931x over previous
//
#include <hip/hip_runtime.h>
#include <hip/hip_bf16.h>
#include <math.h>

// ---------------------------------------------------------------------------
// CausalSelfAttention: B=2, S=2048, D=1024, H=16, Hd=64. f32 in / f32 out.
// R24: verified recombination after R23's correctness failure.
//  - gemm_qkv: R20's (harness-passed) BK=64 + XOR col-swizzle via
//    pre-swizzled global source (fixes 8-way LDS read conflict), plain V.
//  - attn: R17's (harness-passed, 57.4us) swapped-QK^T 16x16 kernel:
//    16 waves/CU, in-register k row-sum, b64 P-spill to wave-private Psh,
//    two-barrier staging with register prefetch, qt swizzle for CU balance.
// R21/R22/R23 lessons: occupancy <16 waves/CU exposes DS/MFMA latency and
// loses more than per-op efficiency gains; multi-mechanism restructures
// must not ship unverified. This build is all previously-passed pieces.
// ---------------------------------------------------------------------------

typedef short bfrag __attribute__((ext_vector_type(8)));   // 8 bf16 = 4 VGPR
typedef float f32x4 __attribute__((ext_vector_type(4)));

__device__ __forceinline__ float bf2f(ushort u) {
    union { uint i; float f; } v; v.i = ((uint)u) << 16; return v.f;
}
__device__ __forceinline__ ushort f2bf(float f) {
    union { uint i; float f; } v; v.f = f;
    uint u = v.i;
    return (ushort)((u + 0x7fffu + ((u >> 16) & 1u)) >> 16);  // RNE
}

#define MFMA16 __builtin_amdgcn_mfma_f32_16x16x32_bf16

__device__ __forceinline__ void gl_lds16(const ushort* g, ushort* l) {
    __builtin_amdgcn_global_load_lds(
        (const __attribute__((address_space(1))) void*)g,
        (__attribute__((address_space(3))) void*)l, 16, 0, 0);
}

// ---------------------------------------------------------------------------
// Kernel 0a: f32 -> bf16 convert (xb = x; wb = [Wq;Wkv]).
// ---------------------------------------------------------------------------
__global__ __launch_bounds__(256)
void cvt_bf16(const float* __restrict__ x, const float* __restrict__ wq,
              const float* __restrict__ wkv, ushort* __restrict__ xb,
              ushort* __restrict__ wb)
{
    const size_t NX = 4096u * 1024u, NWQ = 1024u * 1024u;
    size_t i8 = ((size_t)blockIdx.x * 256 + threadIdx.x) * 8;
    const float* src;
    ushort* dst;
    if (i8 < NX) { src = x + i8; dst = xb + i8; }
    else {
        size_t j = i8 - NX;
        dst = wb + j;
        src = (j < NWQ) ? (wq + j) : (wkv + (j - NWQ));
    }
    float4 a = *(const float4*)(src);
    float4 c = *(const float4*)(src + 4);
    ushort u[8];
    u[0] = f2bf(a.x); u[1] = f2bf(a.y); u[2] = f2bf(a.z); u[3] = f2bf(a.w);
    u[4] = f2bf(c.x); u[5] = f2bf(c.y); u[6] = f2bf(c.z); u[7] = f2bf(c.w);
    *(uint4*)dst = *(uint4*)u;
}

// ---------------------------------------------------------------------------
// Kernel 0b: rope table tab[s][fi] = (cos,sin)(s * 10000^(-fi/32)).
// ---------------------------------------------------------------------------
__global__ __launch_bounds__(256)
void rope_table(float2* __restrict__ tab)
{
    int t  = blockIdx.x * 256 + threadIdx.x;   // 65536
    int fi = t & 31, s = t >> 5;
    float invf = (float)exp((double)fi * -0.28782313662425574);
    float thf  = (float)s * invf;
    const double TWO_PI = 6.283185307179586476925287;
    double th = (double)thf;
    double kq = __builtin_rint(th * (1.0 / TWO_PI));
    float r = (float)(th - kq * TWO_PI);
    tab[t] = make_float2(cosf(r), sinf(r));
}

// ---------------------------------------------------------------------------
// Kernel 1 (R20, passed): QKV GEMM, BK=64, swizzled LDS (conflict-free frag
// reads via pre-swizzled global source + linear gl_lds dest), fused RoPE,
// plain V-transpose store.
// ---------------------------------------------------------------------------
__global__ __launch_bounds__(256)
void gemm_qkv(const ushort* __restrict__ xb, const ushort* __restrict__ wb,
              const float2* __restrict__ tab, ushort* __restrict__ Qb,
              ushort* __restrict__ Kb, ushort* __restrict__ Vt)
{
    __shared__ ushort Ash[128][64];
    __shared__ ushort Bsh[128][64];

    const int tid  = threadIdx.x;
    const int lane = tid & 63, wv = tid >> 6;
    const int quad = lane >> 4, li = lane & 15;
    const int m0 = blockIdx.x * 128, n0 = blockIdx.y * 128;

    f32x4 acc[2][8];
#pragma unroll
    for (int mi = 0; mi < 2; mi++)
#pragma unroll
        for (int j = 0; j < 8; j++) acc[mi][j] = (f32x4){0.f, 0.f, 0.f, 0.f};

    const int r8  = lane >> 3;
    const int gch = ((lane & 7) ^ r8) * 8;
    const ushort* gA = xb + (size_t)(m0 + wv * 32 + r8) * 1024 + gch;
    const ushort* gB = wb + (size_t)(n0 + wv * 32 + r8) * 1024 + gch;

    for (int k0 = 0; k0 < 1024; k0 += 64) {
        __syncthreads();
#pragma unroll
        for (int c = 0; c < 4; c++) {
            gl_lds16(gA + (size_t)(c * 8) * 1024 + k0, &Ash[wv * 32 + c * 8][0]);
            gl_lds16(gB + (size_t)(c * 8) * 1024 + k0, &Bsh[wv * 32 + c * 8][0]);
        }
        __syncthreads();

        const int sw = li & 7;
#pragma unroll
        for (int ks = 0; ks < 2; ks++) {
            bfrag af[2], bf[8];
#pragma unroll
            for (int mi = 0; mi < 2; mi++)
                af[mi] = *(const bfrag*)
                    &Ash[wv * 32 + mi * 16 + li][(((ks << 2) | quad) ^ sw) * 8];
#pragma unroll
            for (int j = 0; j < 8; j++)
                bf[j] = *(const bfrag*)
                    &Bsh[j * 16 + li][(((ks << 2) | quad) ^ sw) * 8];
#pragma unroll
            for (int mi = 0; mi < 2; mi++)
#pragma unroll
                for (int j = 0; j < 8; j++)
                    acc[mi][j] = MFMA16(af[mi], bf[j], acc[mi][j], 0, 0, 0);
        }
    }

    if (n0 < 1024) {
        const int hbase = n0 >> 6;
#pragma unroll
        for (int mi = 0; mi < 2; mi++)
#pragma unroll
            for (int r = 0; r < 4; r++) {
                int m = m0 + wv * 32 + mi * 16 + quad * 4 + r;
                int bb = m >> 11, s = m & 2047;
                float2 t0 = tab[s * 32 + li];
                float2 t1 = tab[s * 32 + li + 16];
#pragma unroll
                for (int j = 0; j < 8; j++) {
                    float v  = acc[mi][j][r];
                    float vp = acc[mi][j ^ 2][r];
                    float2 tt = (j & 1) ? t1 : t0;
                    float rh = (j & 2) ? vp : -vp;
                    int h = hbase + (j >> 2), hd = (j & 3) * 16 + li;
                    Qb[(size_t)((bb * 16 + h) * 2048 + s) * 64 + hd] =
                        f2bf(v * tt.x + rh * tt.y);
                }
            }
    } else {
        const int h = (n0 - 1024) >> 7;
        const int li2 = li >> 1;
        if ((li & 1) == 0) {
#pragma unroll
            for (int mi = 0; mi < 2; mi++)
#pragma unroll
                for (int r = 0; r < 4; r++) {
                    int m = m0 + wv * 32 + mi * 16 + quad * 4 + r;
                    int bb = m >> 11, s = m & 2047;
                    float2 tt4[4];
#pragma unroll
                    for (int jj = 0; jj < 4; jj++)
                        tt4[jj] = tab[s * 32 + jj * 8 + li2];
#pragma unroll
                    for (int j = 0; j < 8; j++) {
                        float v  = acc[mi][j][r];
                        float vp = acc[mi][j ^ 4][r];
                        float2 tt = tt4[j & 3];
                        float rh = (j & 4) ? vp : -vp;
                        int hd = j * 8 + li2;
                        Kb[(size_t)((bb * 16 + h) * 2048 + s) * 64 + hd] =
                            f2bf(v * tt.x + rh * tt.y);
                    }
                }
        } else {
#pragma unroll
            for (int mi = 0; mi < 2; mi++) {
                int m4 = m0 + wv * 32 + mi * 16 + quad * 4;
                int bb = m4 >> 11, s0 = m4 & 2047;
#pragma unroll
                for (int j = 0; j < 8; j++) {
                    int hd = j * 8 + li2;
                    ushort u4[4];
#pragma unroll
                    for (int r = 0; r < 4; r++) u4[r] = f2bf(acc[mi][j][r]);
                    *(ushort4*)&Vt[(size_t)((bb * 16 + h) * 64 + hd) * 2048 + s0] =
                        *(ushort4*)u4;
                }
            }
        }
    }
}

// ---------------------------------------------------------------------------
// Kernel 2 (R17, passed @57.4us): causal flash attention, swapped-QK^T
// in-register softmax. 1 WG (256 thr) = (b,h) x 64-row Q-tile; wave w owns
// 16 rows (q = li). Scores via mfma(K,Q): lane holds S[k][q=li]. Row-sum =
// 16 reg adds + shfl_xor(16,32). P spilled as 4x ds_write_b64, read back as
// A-fragment. Mask on diagonal tile only; no-max exp2; truncation-consistent
// rsum. Two-barrier staging with register prefetch; qt swizzle for balance.
// ---------------------------------------------------------------------------
__global__ __launch_bounds__(256)
void attn(const ushort* __restrict__ Qb, const ushort* __restrict__ Kb,
          const ushort* __restrict__ Vt, float* __restrict__ out)
{
    __shared__ ushort Ksh[64][72];
    __shared__ ushort Vsh[64][72];
    __shared__ ushort Psh[4][16][72];

    const int tid  = threadIdx.x;
    const int lane = tid & 63, w = tid >> 6;
    const int quad = lane >> 4, li = lane & 15;
    const int qt = ((31 - (int)blockIdx.x) + (int)blockIdx.y) & 31;
    const int bh = blockIdx.y;
    const int b = bh >> 4, h = bh & 15;

    const int qrow = qt * 64 + w * 16 + li;      // this lane's q (swapped layout)
    const ushort* qp = Qb + (size_t)(bh * 2048 + qrow) * 64;
    bfrag qa0 = *(const bfrag*)(qp + quad * 8);
    bfrag qa1 = *(const bfrag*)(qp + quad * 8 + 32);

    f32x4 o[4];
#pragma unroll
    for (int j = 0; j < 4; j++) o[j] = (f32x4){0.f, 0.f, 0.f, 0.f};
    float lrow = 0.f;                            // running denom for q = li

    const int srow = tid >> 2, sc0 = (tid & 3) * 16;
    const ushort* kbase = Kb + (size_t)bh * 2048 * 64;
    const ushort* vbase = Vt + (size_t)bh * 64 * 2048;

    // preload kt=0 (16 VGPRs of prefetch state — no spill at this size)
    uint4 ka, kb_, va, vb_;
    {
        const ushort* gk = kbase + (size_t)srow * 64 + sc0;
        ka  = *(const uint4*)gk;
        kb_ = *(const uint4*)(gk + 8);
        const ushort* gv = vbase + (size_t)srow * 2048 + sc0;
        va  = *(const uint4*)gv;
        vb_ = *(const uint4*)(gv + 8);
    }

    const float C = 0.125f * 1.4426950408889634f;   // scale * log2(e)

    for (int kt = 0; kt <= qt; ++kt) {
        __syncthreads();
        *(uint4*)&Ksh[srow][sc0]     = ka;
        *(uint4*)&Ksh[srow][sc0 + 8] = kb_;
        *(uint4*)&Vsh[srow][sc0]     = va;
        *(uint4*)&Vsh[srow][sc0 + 8] = vb_;
        __syncthreads();

        if (kt < qt) {     // prefetch next tile; latency hidden by compute
            const ushort* gk = kbase + (size_t)((kt + 1) * 64 + srow) * 64 + sc0;
            ka  = *(const uint4*)gk;
            kb_ = *(const uint4*)(gk + 8);
            const ushort* gv = vbase + (size_t)srow * 2048 + (kt + 1) * 64 + sc0;
            va  = *(const uint4*)gv;
            vb_ = *(const uint4*)(gv + 8);
        }

        // --- scores, swapped: sc[j][r] = S[k = kt*64+j*16+quad*4+r][q = li] ---
        f32x4 sc[4];
        __builtin_amdgcn_s_setprio(1);
#pragma unroll
        for (int j = 0; j < 4; j++) {
            bfrag kb0 = *(const bfrag*)&Ksh[j * 16 + li][quad * 8];
            bfrag kb1 = *(const bfrag*)&Ksh[j * 16 + li][quad * 8 + 32];
            f32x4 z = (f32x4){0.f, 0.f, 0.f, 0.f};
            z = MFMA16(kb0, qa0, z, 0, 0, 0);
            z = MFMA16(kb1, qa1, z, 0, 0, 0);
            sc[j] = z;
        }
        __builtin_amdgcn_s_setprio(0);

        // --- causal mask: only the diagonal tile needs it ---
        if (kt == qt) {
#pragma unroll
            for (int j = 0; j < 4; j++) {
                int kg0 = kt * 64 + j * 16 + quad * 4;
#pragma unroll
                for (int r = 0; r < 4; r++)
                    sc[j][r] = (kg0 + r <= qrow) ? sc[j][r] : -3.0e38f;
            }
        }

        // --- P = exp2(sc*C); lane's 4 values per j are consecutive in k ---
        float rs = 0.f;
#pragma unroll
        for (int j = 0; j < 4; j++) {
            ushort pk[4];
#pragma unroll
            for (int r = 0; r < 4; r++) {
                float pv = exp2f(sc[j][r] * C);
                uint pu = __float_as_uint(pv);
                pk[r] = (ushort)(pu >> 16);
                rs += __uint_as_float(pu & 0xffff0000u);  // consistent w/ P
            }
            *(ushort4*)&Psh[w][li][j * 16 + quad * 4] = *(ushort4*)pk;
        }
        // complete row-sum for q=li across the 4 quads
        rs += __shfl_xor(rs, 16);
        rs += __shfl_xor(rs, 32);
        lrow += rs;

        // --- P: LDS -> A-fragment (wave-private Psh) ---
        asm volatile("s_waitcnt lgkmcnt(0)" ::: "memory");
        bfrag pa0 = *(const bfrag*)&Psh[w][li][quad * 8];
        bfrag pa1 = *(const bfrag*)&Psh[w][li][quad * 8 + 32];

        __builtin_amdgcn_s_setprio(1);
#pragma unroll
        for (int j = 0; j < 4; j++) {
            bfrag vb0 = *(const bfrag*)&Vsh[j * 16 + li][quad * 8];
            bfrag vb1 = *(const bfrag*)&Vsh[j * 16 + li][quad * 8 + 32];
            o[j] = MFMA16(pa0, vb0, o[j], 0, 0, 0);
            o[j] = MFMA16(pa1, vb1, o[j], 0, 0, 0);
        }
        __builtin_amdgcn_s_setprio(0);
    }

    // epilogue: redistribute l (held at lane li == q) to q = quad*4+r
    float lf[4];
#pragma unroll
    for (int r = 0; r < 4; r++)
        lf[r] = __shfl(lrow, (lane & 48) + quad * 4 + r);

#pragma unroll
    for (int j = 0; j < 4; j++)
#pragma unroll
        for (int r = 0; r < 4; r++) {
            int s = qt * 64 + w * 16 + quad * 4 + r;
            out[(size_t)(b * 2048 + s) * 1024 + h * 64 + j * 16 + li] =
                o[j][r] / lf[r];
        }
}

// ---------------------------------------------------------------------------
extern "C" void kernel_launch(void* const* d_in, const int* in_sizes, int n_in,
                              void* d_out, int out_size, void* d_ws, size_t ws_size,
                              hipStream_t stream)
{
    (void)in_sizes; (void)n_in; (void)out_size; (void)ws_size;
    const float* x   = (const float*)d_in[0];   // (2,2048,1024) f32
    const float* wq  = (const float*)d_in[1];   // (1024,1024)  f32
    const float* wkv = (const float*)d_in[2];   // (2048,1024)  f32
    // d_in[3] = causal mask — computed analytically

    ushort* xb = (ushort*)d_ws;                       // 4096x1024 bf16
    ushort* wb = xb + (size_t)4096 * 1024;            // 3072x1024 bf16
    float2* tab = (float2*)(wb + (size_t)3072 * 1024); // 2048x32 (cos,sin)
    ushort* Qb = (ushort*)(tab + 65536);              // (B,H,S,Hd)
    ushort* Kb = Qb + (size_t)2 * 16 * 2048 * 64;     // (B,H,S,Hd)
    ushort* Vt = Kb + (size_t)2 * 16 * 2048 * 64;     // (B,H,Hd,S)
    float* out = (float*)d_out;                       // f32 output

    cvt_bf16<<<3584, 256, 0, stream>>>(x, wq, wkv, xb, wb);
    rope_table<<<256, 256, 0, stream>>>(tab);
    dim3 g1(32, 24);
    gemm_qkv<<<g1, 256, 0, stream>>>(xb, wb, tab, Qb, Kb, Vt);
    dim3 g4(32, 32);
    attn<<<g4, 256, 0, stream>>>(Qb, Kb, Vt, out);
}